// Round 7
// baseline (492.286 us; speedup 1.0000x reference)
//
#include <hip/hip_runtime.h>

#define NF   16
#define C    8
#define NB   4
#define NPIX (512*512)
#define NBLKX 256
#define NBLK  (NBLKX * NB)   // 1024 blocks, all co-resident (4/CU: LDS ~35KB, VGPR<=128)
#define PXB  1024            // pixels per block
#define ITERS 4              // 4 iters x 256 px

// ws float layout:
//   [0,512)    sums[b][c*16+f]
//   [512,544)  counts[b*8+c]
//   [544]      barrier flag (int)
#define WS_CNT   512
#define WS_FLAG  544
#define WS_TOTAL 548

__global__ void init_kernel(float* __restrict__ ws, float* __restrict__ out) {
    int t = blockIdx.x * blockDim.x + threadIdx.x;
    if (t < WS_TOTAL) ws[t] = 0.0f;
    if (t == 0) out[0] = 0.0f;
}

__device__ inline unsigned bf16pack2(float a, float b) {   // RTNE bf16 pair
    unsigned ua = __float_as_uint(a); ua = (ua + 0x7FFFu + ((ua >> 16) & 1u)) >> 16;
    unsigned ub = __float_as_uint(b); ub = (ub + 0x7FFFu + ((ub >> 16) & 1u)) >> 16;
    return ua | (ub << 16);
}
__device__ inline float bf16lo(unsigned u) { return __uint_as_float(u << 16); }
__device__ inline float bf16hi(unsigned u) { return __uint_as_float(u & 0xFFFF0000u); }

// Single-pass fused kernel: pred read from global exactly once, parked in LDS
// as bf16 [f][px]. Cross-block combine via ws atomics + device-wide spin
// barrier; read-back uses agent-scope atomic LOADS (no RMW storm).
__global__ __launch_bounds__(256, 4) void fused_kernel(const float* __restrict__ pred,
                                                       const int* __restrict__ tgt,
                                                       float* __restrict__ ws,
                                                       float* __restrict__ out) {
    __shared__ unsigned s_pred[NF * PXB / 2];   // bf16 pairs, [f][px]: 32 KB
    __shared__ unsigned s_lab[PXB / 4];         // packed labels, 1 KB
    __shared__ float    s_raw[136];
    __shared__ float    s_means[128];           // [f*8+c]
    __shared__ float    s_inv;
    __shared__ float    s_red[4];

    const int tid  = threadIdx.x;
    const int lane = tid & 63;
    const int wave = tid >> 6;          // 0..3
    const int b    = blockIdx.y;
    const int f0   = wave * 4;
    const int px0  = blockIdx.x * PXB;  // block-global pixel base

    const float* predb = pred + (size_t)b * NF * NPIX;
    const int*   tgtb  = tgt  + (size_t)b * NPIX;

    // ---- labels: wave w loads iteration w (parallel across waves), counts its slice ----
    float cnt[C];
#pragma unroll
    for (int c = 0; c < C; ++c) cnt[c] = 0.0f;
    {
        int4 lb = *(const int4*)(tgtb + px0 + wave * 256 + lane * 4);
        s_lab[wave * 64 + lane] = (unsigned)(lb.x | (lb.y << 8) | (lb.z << 16) | (lb.w << 24));
#pragma unroll
        for (int c = 0; c < C; ++c)
            cnt[c] += (lb.x == c ? 1.f : 0.f) + (lb.y == c ? 1.f : 0.f)
                    + (lb.z == c ? 1.f : 0.f) + (lb.w == c ? 1.f : 0.f);
    }
    __syncthreads();

    // ---- phase 1: load pred once, masked sums, park bf16 in LDS ----
    float acc[4][C];
#pragma unroll
    for (int fi = 0; fi < 4; ++fi)
#pragma unroll
        for (int c = 0; c < C; ++c) acc[fi][c] = 0.0f;

#pragma unroll
    for (int it = 0; it < ITERS; ++it) {
        const int pxi = it * 256 + lane * 4;    // block-local pixel
        float4 q[4];
#pragma unroll
        for (int fi = 0; fi < 4; ++fi)
            q[fi] = *(const float4*)(predb + (size_t)(f0 + fi) * NPIX + px0 + pxi);
        const unsigned lp = s_lab[it * 64 + lane];
        const int c0 = lp & 255, c1 = (lp >> 8) & 255, c2 = (lp >> 16) & 255, c3 = lp >> 24;
#pragma unroll
        for (int c = 0; c < C; ++c) {
            const float mx = (c0 == c) ? 1.f : 0.f;
            const float my = (c1 == c) ? 1.f : 0.f;
            const float mz = (c2 == c) ? 1.f : 0.f;
            const float mw = (c3 == c) ? 1.f : 0.f;
#pragma unroll
            for (int fi = 0; fi < 4; ++fi)
                acc[fi][c] += mx * q[fi].x + my * q[fi].y + mz * q[fi].z + mw * q[fi].w;
        }
#pragma unroll
        for (int fi = 0; fi < 4; ++fi) {
            uint2 pk = make_uint2(bf16pack2(q[fi].x, q[fi].y), bf16pack2(q[fi].z, q[fi].w));
            *(uint2*)&s_pred[((f0 + fi) * PXB + pxi) >> 1] = pk;
        }
    }

    // wave butterfly reduce; lane 0 commits (distinct addresses -> pipelined RMWs)
#pragma unroll
    for (int off = 32; off > 0; off >>= 1) {
#pragma unroll
        for (int fi = 0; fi < 4; ++fi)
#pragma unroll
            for (int c = 0; c < C; ++c)
                acc[fi][c] += __shfl_down(acc[fi][c], off);
#pragma unroll
        for (int c = 0; c < C; ++c) cnt[c] += __shfl_down(cnt[c], off);
    }
    if (lane == 0) {
        float* gsum = ws + b * (C * NF);
#pragma unroll
        for (int fi = 0; fi < 4; ++fi)
#pragma unroll
            for (int c = 0; c < C; ++c)
                atomicAdd(&gsum[c * NF + (f0 + fi)], acc[fi][c]);
#pragma unroll
        for (int c = 0; c < C; ++c)
            atomicAdd(&ws[WS_CNT + b * C + c], cnt[c]);
    }

    // ---- device-wide barrier (all 1024 blocks co-resident) ----
    __threadfence();
    __syncthreads();
    int* flag = (int*)(ws + WS_FLAG);
    if (tid == 0) {
        atomicAdd(flag, 1);
        while (__hip_atomic_load(flag, __ATOMIC_ACQUIRE, __HIP_MEMORY_SCOPE_AGENT) < NBLK)
            __builtin_amdgcn_s_sleep(32);
    }
    __syncthreads();

    // ---- means: coherent agent-scope LOADS (pipelined, no RMW serialization) ----
    if (tid < 136) {
        const int gidx = (tid < 128) ? (b * 128 + tid) : (WS_CNT + b * C + (tid - 128));
        s_raw[tid] = __hip_atomic_load(&ws[gidx], __ATOMIC_RELAXED, __HIP_MEMORY_SCOPE_AGENT);
    }
    __syncthreads();
    if (tid < 128) {
        const int c = tid >> 4, f = tid & 15;
        s_means[f * C + c] = s_raw[c * NF + f] / s_raw[128 + c];
    }
    if (tid == 224) {
        float is = 0.0f;
#pragma unroll
        for (int c = 0; c < C; ++c) is += 1.0f / s_raw[128 + c];
        s_inv = is;
    }
    __syncthreads();

    // ---- phase 2: thread t owns pixels 4t..4t+3, reads pred back from LDS ----
    const unsigned labd = s_lab[tid];
    const int c0 = labd & 255, c1 = (labd >> 8) & 255, c2 = (labd >> 16) & 255, c3 = labd >> 24;
    float s0 = 0.f, s1 = 0.f, s2 = 0.f, s3 = 0.f;
#pragma unroll
    for (int f = 0; f < NF; ++f) {
        uint2 hv = *(const uint2*)&s_pred[f * (PXB / 2) + tid * 2];
        float d0 = s_means[f * C + c0] - bf16lo(hv.x);
        float d1 = s_means[f * C + c1] - bf16hi(hv.x);
        float d2 = s_means[f * C + c2] - bf16lo(hv.y);
        float d3 = s_means[f * C + c3] - bf16hi(hv.y);
        s0 += d0 * d0; s1 += d1 * d1; s2 += d2 * d2; s3 += d3 * d3;
    }
    float t0 = fminf(fmaxf(sqrtf(s0) - 0.5f, 0.0f), 100000.0f);
    float t1 = fminf(fmaxf(sqrtf(s1) - 0.5f, 0.0f), 100000.0f);
    float t2 = fminf(fmaxf(sqrtf(s2) - 0.5f, 0.0f), 100000.0f);
    float t3 = fminf(fmaxf(sqrtf(s3) - 0.5f, 0.0f), 100000.0f);
    float accd = t0 * t0 + t1 * t1 + t2 * t2 + t3 * t3;

#pragma unroll
    for (int off = 32; off > 0; off >>= 1) accd += __shfl_down(accd, off);
    if (lane == 0) s_red[wave] = accd;
    __syncthreads();
    if (tid == 0)
        atomicAdd(out, (s_red[0] + s_red[1] + s_red[2] + s_red[3]) * s_inv * 0.125f);
}

extern "C" void kernel_launch(void* const* d_in, const int* in_sizes, int n_in,
                              void* d_out, int out_size, void* d_ws, size_t ws_size,
                              hipStream_t stream) {
    const float* pred = (const float*)d_in[0];
    const int*   tgt  = (const int*)d_in[1];
    float* out = (float*)d_out;
    float* ws  = (float*)d_ws;

    init_kernel<<<dim3((WS_TOTAL + 255) / 256), dim3(256), 0, stream>>>(ws, out);
    fused_kernel<<<dim3(NBLKX, NB), dim3(256), 0, stream>>>(pred, tgt, ws, out);
}